// Round 1
// baseline (71.398 us; speedup 1.0000x reference)
//
#include <hip/hip_runtime.h>

// Problem: B=16, M=N=64, P=Q=3, OUT_U=OUT_V=256, f32 in/out.
// Reference quirks kept faithful:
//  - V is built from knot_u (source bug) and u==v linspace, P==Q
//    => v-direction spans & basis are IDENTICAL to u-direction.
//  - Output keeps only comps 0..2 of the 4-comp ctrl points.
//  - np.cumsum is sequential; mirrored exactly (single-thread f32 chain).
//
// R6: FUSED single kernel (was: basis_kernel -> ws -> eval_kernel).
//  Rationale: both old kernels are far below the 41µs ws-poison fills in
//  rocprof; op roofline is ~2µs. The cost is the serialized 2-kernel chain
//  + the latency-bound 16-block basis kernel. Since u and v sample the
//  SAME linspace against the SAME normalized knot vector, each block's
//  two Nu fragments are just the Nv values of threads tid==u0/u0+1.
//  So each of the 2048 blocks recomputes the (L2-hot, 68-float) knot
//  cumsum + its own per-thread basis and never touches the workspace.
//
//  Per block (b, u-pair):
//   0: 68 threads stage knot row -> LDS; thread 0 sequential cumsum+norm
//      (exact np.cumsum f32 order).
//   1: every thread: span + cubic Cox-de Boor for t=linspace[tid]
//      (this is its own Nv, kept in registers); threads u0,u0+1 publish
//      theirs to LDS as the block's Nu.
//   2: 192 threads build rowU[j][col] = sum_l Nu[l]*ctrl[row_l][col]
//   3: per thread 2 points: 8x LDS float4 read + 24 FMA -> LDS obuf
//   4: coalesced float4 stores of the 6 KB contiguous block output.
constexpr int B_   = 16;
constexpr int M_   = 64;
constexpr int N_   = 64;
constexpr int DEG  = 3;
constexpr int T_   = 256;   // OUT_U == OUT_V
constexpr int KLEN = 68;    // M + P + 1

__global__ __launch_bounds__(256)
void surf_kernel(const float* __restrict__ ctrl,
                 const float* __restrict__ knot_u,
                 float*       __restrict__ out) {
    const int b   = blockIdx.x >> 7;          // 2048 blocks: 16 b × 128 u-pairs
    const int u0  = (blockIdx.x & 127) * 2;   // first of two u's
    const int tid = threadIdx.x;              // v-sample

    __shared__ float  raw[KLEN];              // raw knot row
    __shared__ float  su[KLEN];               // normalized cumsum
    __shared__ float4 uN[2];                  // u-basis for the block's 2 u's
    __shared__ int    uS[2];                  // u-spans
    __shared__ float4 rowU[2][N_];            // u-contracted ctrl rows (2 u's)
    __shared__ __align__(16) float obuf[2 * T_ * 3];  // 6 KB output staging

    // phase 0a: coalesced knot load (272 B, L2-hot after first block of this b)
    if (tid < KLEN) raw[tid] = knot_u[b * KLEN + tid];
    __syncthreads();

    // phase 0b: exact sequential cumsum + normalize (mirrors np.cumsum order)
    if (tid == 0) {
        float acc = 0.f;
        #pragma unroll
        for (int i = 0; i < KLEN; ++i) { acc += raw[i]; su[i] = acc; }
        const float c0 = su[0];
        const float d  = su[KLEN - 1] - c0;
        #pragma unroll
        for (int i = 0; i < KLEN; ++i) su[i] = (su[i] - c0) / d;
    }
    __syncthreads();

    // phase 1a: per-thread span + cubic basis, t = linspace(1e-5,1-1e-5,256)[tid]
    const float tt = 1e-5f + (float)tid * ((1.0f - 2e-5f) / 255.0f);

    // span: first-occurrence argmin of (t - U[s+3]) where > 1e-8 else 1.0
    float best = 1e30f; int bs = 0;
    #pragma unroll
    for (int s = 0; s < KLEN - 2 * DEG; ++s) {       // 62 candidates, LDS broadcast
        float dd   = tt - su[s + DEG];
        float cand = (dd > 1e-8f) ? dd : 1.0f;
        if (cand < best) { best = cand; bs = s; }    // strict < keeps first min
    }
    const int span = bs + DEG;

    // Cox-de Boor, degree 3, exact reference arithmetic order
    float Ni[4] = {1.f, 0.f, 0.f, 0.f};
    #pragma unroll
    for (int k = 1; k <= DEG; ++k) {
        float saved = 0.f;
        #pragma unroll
        for (int r = 0; r < k; ++r) {
            const float K1   = su[span + r + 1];
            const float K2   = su[span + 1 - k + r];
            const float temp = Ni[r] / ((K1 - tt) + (tt - K2));
            Ni[r] = saved + (K1 - tt) * temp;
            saved = (tt - K2) * temp;
        }
        Ni[k] = saved;
    }

    // phase 1b: u-samples are the same linspace -> threads u0, u0+1 publish
    // their basis as the block's Nu (bit-identical to the old ws_basis path).
    if (tid == u0 || tid == u0 + 1) {
        uN[tid - u0] = make_float4(Ni[0], Ni[1], Ni[2], Ni[3]);
        uS[tid - u0] = span;
    }
    __syncthreads();

    // phase 2: rowU[j][col][c] = sum_l Nu[l]*ctrl[row_l][col][c]
    // (u-basis lookups are block-uniform LDS broadcast reads)
    if (tid < 3 * N_) {
        const int col = tid / 3;       // 0..63
        const int c   = tid - col * 3; // 0..2
        #pragma unroll
        for (int j = 0; j < 2; ++j) {
            const float4 Nu = uN[j];
            const int    us = uS[j];
            const float NuA[4] = {Nu.x, Nu.y, Nu.z, Nu.w};
            float acc = 0.f;
            #pragma unroll
            for (int l = 0; l < 4; ++l) {
                int row = us - DEG + l;
                row = row < 0 ? 0 : (row > M_ - 1 ? M_ - 1 : row);   // JAX clip
                acc += NuA[l] * ctrl[((size_t)(b * M_ + row) * N_ + col) * 4 + c];
            }
            ((float*)&rowU[j][col])[c] = acc;
        }
    }
    __syncthreads();

    // phase 3: v-contraction for both u's (own Nv in registers) -> LDS staging
    #pragma unroll
    for (int j = 0; j < 2; ++j) {
        float a0 = 0.f, a1 = 0.f, a2 = 0.f;
        #pragma unroll
        for (int r = 0; r < 4; ++r) {
            int col = span - DEG + r;
            col = col < 0 ? 0 : (col > N_ - 1 ? N_ - 1 : col);       // JAX clip
            const float4 cp = rowU[j][col];
            a0 += Ni[r] * cp.x;
            a1 += Ni[r] * cp.y;
            a2 += Ni[r] * cp.z;
        }
        // stride-3 dword writes: 3 is coprime with 32 banks -> conflict-free
        obuf[(j * T_ + tid) * 3 + 0] = a0;
        obuf[(j * T_ + tid) * 3 + 1] = a1;
        obuf[(j * T_ + tid) * 3 + 2] = a2;
    }
    __syncthreads();

    // phase 4: coalesced float4 stores (1536 floats = 384 float4, contiguous 6 KB)
    float4*       dst = (float4*)(out + (size_t)(b * T_ + u0) * T_ * 3);
    const float4* src = (const float4*)obuf;
    dst[tid] = src[tid];
    if (tid < 128) dst[T_ + tid] = src[T_ + tid];
}

extern "C" void kernel_launch(void* const* d_in, const int* in_sizes, int n_in,
                              void* d_out, int out_size, void* d_ws, size_t ws_size,
                              hipStream_t stream) {
    const float* ctrl   = (const float*)d_in[0];
    const float* knot_u = (const float*)d_in[1];
    // d_in[2] (knot_v) unused: reference builds V from knot_u.
    float* out = (float*)d_out;
    (void)d_ws; (void)ws_size; (void)in_sizes; (void)n_in; (void)out_size;

    // Single fused dispatch; workspace no longer used.
    surf_kernel<<<dim3(B_ * T_ / 2), dim3(T_), 0, stream>>>(ctrl, knot_u, out);
}

// Round 4
// 68.186 us; speedup vs baseline: 1.0471x; 1.0471x over previous
//
#include <hip/hip_runtime.h>

// Problem: B=16, M=N=64, P=Q=3, OUT_U=OUT_V=256, f32 in/out.
// Reference quirks kept faithful:
//  - V is built from knot_u (source bug) and u==v linspace, P==Q
//    => v-direction spans & basis are IDENTICAL to u-direction.
//  - Output keeps only comps 0..2 of the 4-comp ctrl points.
//
// R9: fused kernel + parallel-prefix cumsum, SHUFFLE-FREE variant.
//  R2/R3 benches died in infra ("container failed twice") before running
//  R7's shfl-scan version. Same optimization theory (remove R6's per-block
//  serial thread-0 section: 68-add dependent chain + 68 serial precise
//  divides ~1.5us x 2048 blocks), implemented without cross-lane ops:
//  each of 68 threads computes its own prefix sum cs[i] = sum_{j<=i} raw[j]
//  via a predicated loop over LDS-broadcast reads (<=68 iters, parallel
//  across lanes). This is BITWISE-identical to np.cumsum per element
//  (increasing-j f32 order), so no reassociation risk at all.
//
//  Per block (b, u-pair):
//   0: 68 threads stage knot row -> LDS; 68 threads parallel prefix-sum
//      (broadcast reads); 68 threads parallel normalize (exact formula).
//   1: every thread: span + cubic Cox-de Boor for t=linspace[tid]
//      (its own Nv, in registers); threads u0,u0+1 publish theirs as Nu.
//   2: 192 threads build rowU[j][col] = sum_l Nu[l]*ctrl[row_l][col]
//   3: per thread 2 points: 8x LDS float4 read + 24 FMA -> LDS obuf
//   4: coalesced float4 stores of the 6 KB contiguous block output.
constexpr int B_   = 16;
constexpr int M_   = 64;
constexpr int N_   = 64;
constexpr int DEG  = 3;
constexpr int T_   = 256;   // OUT_U == OUT_V
constexpr int KLEN = 68;    // M + P + 1

__global__ __launch_bounds__(256)
void surf_kernel(const float* __restrict__ ctrl,
                 const float* __restrict__ knot_u,
                 float*       __restrict__ out) {
    const int b   = blockIdx.x >> 7;          // 2048 blocks: 16 b × 128 u-pairs
    const int u0  = (blockIdx.x & 127) * 2;   // first of two u's
    const int tid = threadIdx.x;              // v-sample

    __shared__ float  raw[KLEN];              // raw knot row
    __shared__ float  cs[KLEN];               // cumsum
    __shared__ float  sn[KLEN];               // normalized knots
    __shared__ float4 uN[2];                  // u-basis for the block's 2 u's
    __shared__ int    uS[2];                  // u-spans
    __shared__ float4 rowU[2][N_];            // u-contracted ctrl rows (2 u's)
    __shared__ __align__(16) float obuf[2 * T_ * 3];  // 6 KB output staging

    // ---- phase 0a: stage knot row (272 B, L2-hot after first block of b) ----
    if (tid < KLEN) raw[tid] = knot_u[b * KLEN + tid];
    __syncthreads();

    // ---- phase 0b: parallel prefix sums, bitwise == np.cumsum per element.
    //      Thread i sums raw[0..i] in increasing-j f32 order (predicated
    //      loop; LDS reads are same-address broadcasts, conflict-free). ----
    if (tid < KLEN) {
        float acc = 0.f;
        for (int j = 0; j <= tid; ++j) acc += raw[j];
        cs[tid] = acc;
    }
    __syncthreads();

    // ---- phase 0c: parallel normalize, exact per-element formula ----
    {
        const float c0 = cs[0];
        const float d  = cs[KLEN - 1] - c0;
        if (tid < KLEN) sn[tid] = (cs[tid] - c0) / d;
    }
    __syncthreads();

    // ---- phase 1a: per-thread span + cubic basis ----
    const float tt = 1e-5f + (float)tid * ((1.0f - 2e-5f) / 255.0f);

    // span: first-occurrence argmin of (t - U[s+3]) where > 1e-8 else 1.0
    float best = 1e30f; int bs = 0;
    #pragma unroll
    for (int s = 0; s < KLEN - 2 * DEG; ++s) {       // 62 candidates, LDS broadcast
        float dd   = tt - sn[s + DEG];
        float cand = (dd > 1e-8f) ? dd : 1.0f;
        if (cand < best) { best = cand; bs = s; }    // strict < keeps first min
    }
    const int span = bs + DEG;

    // Cox-de Boor, degree 3, exact reference arithmetic order
    float Ni[4] = {1.f, 0.f, 0.f, 0.f};
    #pragma unroll
    for (int k = 1; k <= DEG; ++k) {
        float saved = 0.f;
        #pragma unroll
        for (int r = 0; r < k; ++r) {
            const float K1   = sn[span + r + 1];
            const float K2   = sn[span + 1 - k + r];
            const float temp = Ni[r] / ((K1 - tt) + (tt - K2));
            Ni[r] = saved + (K1 - tt) * temp;
            saved = (tt - K2) * temp;
        }
        Ni[k] = saved;
    }

    // ---- phase 1b: u-samples are the same linspace -> threads u0, u0+1
    //      publish their basis as the block's Nu ----
    if (tid == u0 || tid == u0 + 1) {
        uN[tid - u0] = make_float4(Ni[0], Ni[1], Ni[2], Ni[3]);
        uS[tid - u0] = span;
    }
    __syncthreads();

    // ---- phase 2: rowU[j][col][c] = sum_l Nu[l]*ctrl[row_l][col][c] ----
    // (u-basis lookups are block-uniform LDS broadcast reads)
    if (tid < 3 * N_) {
        const int col = tid / 3;       // 0..63
        const int c   = tid - col * 3; // 0..2
        #pragma unroll
        for (int j = 0; j < 2; ++j) {
            const float4 Nu = uN[j];
            const int    us = uS[j];
            const float NuA[4] = {Nu.x, Nu.y, Nu.z, Nu.w};
            float acc = 0.f;
            #pragma unroll
            for (int l = 0; l < 4; ++l) {
                int row = us - DEG + l;
                row = row < 0 ? 0 : (row > M_ - 1 ? M_ - 1 : row);   // JAX clip
                acc += NuA[l] * ctrl[((size_t)(b * M_ + row) * N_ + col) * 4 + c];
            }
            ((float*)&rowU[j][col])[c] = acc;
        }
    }
    __syncthreads();

    // ---- phase 3: v-contraction for both u's (own Nv in registers) ----
    #pragma unroll
    for (int j = 0; j < 2; ++j) {
        float a0 = 0.f, a1 = 0.f, a2 = 0.f;
        #pragma unroll
        for (int r = 0; r < 4; ++r) {
            int col = span - DEG + r;
            col = col < 0 ? 0 : (col > N_ - 1 ? N_ - 1 : col);       // JAX clip
            const float4 cp = rowU[j][col];
            a0 += Ni[r] * cp.x;
            a1 += Ni[r] * cp.y;
            a2 += Ni[r] * cp.z;
        }
        // stride-3 dword writes: 3 is coprime with 32 banks -> conflict-free
        obuf[(j * T_ + tid) * 3 + 0] = a0;
        obuf[(j * T_ + tid) * 3 + 1] = a1;
        obuf[(j * T_ + tid) * 3 + 2] = a2;
    }
    __syncthreads();

    // ---- phase 4: coalesced float4 stores (1536 floats, contiguous 6 KB) ----
    float4*       dst = (float4*)(out + (size_t)(b * T_ + u0) * T_ * 3);
    const float4* src = (const float4*)obuf;
    dst[tid] = src[tid];
    if (tid < 128) dst[T_ + tid] = src[T_ + tid];
}

extern "C" void kernel_launch(void* const* d_in, const int* in_sizes, int n_in,
                              void* d_out, int out_size, void* d_ws, size_t ws_size,
                              hipStream_t stream) {
    const float* ctrl   = (const float*)d_in[0];
    const float* knot_u = (const float*)d_in[1];
    // d_in[2] (knot_v) unused: reference builds V from knot_u.
    float* out = (float*)d_out;
    (void)d_ws; (void)ws_size; (void)in_sizes; (void)n_in; (void)out_size;

    // Single fused dispatch; workspace unused.
    surf_kernel<<<dim3(B_ * T_ / 2), dim3(T_), 0, stream>>>(ctrl, knot_u, out);
}